// Round 1
// 738.851 us; speedup vs baseline: 1.1001x; 1.1001x over previous
//
#include <hip/hip_runtime.h>
#include <math.h>

#define N 16
#define C 256
#define H 128
#define W 128
#define GROUP 8
#define KK 9
#define GK2 72
#define HW (H*W)
#define BN_EPS 1e-5f

typedef float f32x4 __attribute__((ext_vector_type(4)));

// ---------------- Kernel 1: global average pool per (n,c) plane ----------------
__global__ __launch_bounds__(256) void pool_kernel(const float* __restrict__ x,
                                                   float* __restrict__ pooled) {
    int plane = blockIdx.x;                       // n*C + c
    const float4* xp = (const float4*)(x + (size_t)plane * HW);
    int t = threadIdx.x;
    float s = 0.f;
#pragma unroll
    for (int i = 0; i < 16; ++i) {                // 16384 floats = 4096 float4 / 256 thr
        float4 v = xp[t + i * 256];
        s += v.x + v.y + v.z + v.w;
    }
    // wave-64 reduce
    for (int off = 32; off > 0; off >>= 1) s += __shfl_down(s, off, 64);
    __shared__ float wsum[4];
    if ((t & 63) == 0) wsum[t >> 6] = s;
    __syncthreads();
    if (t == 0) {
        pooled[plane] = (wsum[0] + wsum[1] + wsum[2] + wsum[3]) * (1.0f / (float)HW);
    }
}

// ---------------- Kernel 2: 1x1 conv -> sigmoid gate -> BN -> softmax ----------------
__global__ __launch_bounds__(256) void weights_kernel(const float* __restrict__ pooled,
                                                      const float* __restrict__ conv_w,
                                                      const float* __restrict__ gate_w,
                                                      const float* __restrict__ gamma,
                                                      const float* __restrict__ beta,
                                                      const float* __restrict__ mean,
                                                      const float* __restrict__ var,
                                                      float* __restrict__ wk) {
    int n = blockIdx.x;
    int t = threadIdx.x;
    __shared__ float ps[C];
    __shared__ float lf[GK2];
    __shared__ float ybn[GK2];
    ps[t] = pooled[n * C + t];                    // blockDim 256 == C
    __syncthreads();
    if (t < GK2) {
        float s = 0.f;
        for (int c = 0; c < C; ++c) s += ps[c] * conv_w[t * C + c];
        lf[t] = s;
    }
    __syncthreads();
    if (t < GK2) {
        float go = 0.f;
        for (int o = 0; o < GK2; ++o) go += lf[o] * gate_w[t * GK2 + o];
        float v = lf[t] / (1.f + expf(-go));      // lf * sigmoid(lf @ gate_w.T)
        float sc = gamma[t] * rsqrtf(var[t] + BN_EPS);
        ybn[t] = (v - mean[t]) * sc + beta[t];
    }
    __syncthreads();
    if (t < GK2) {
        int g = t / KK;
        float m = -INFINITY;
        for (int k = 0; k < KK; ++k) m = fmaxf(m, ybn[g * KK + k]);
        float denom = 0.f;
        for (int k = 0; k < KK; ++k) denom += expf(ybn[g * KK + k] - m);
        wk[n * GK2 + t] = expf(ybn[t] - m) / denom;
    }
}

// ---------------- Kernel 3: 3x3 dynamic filter + residual ----------------
// Each block: 8 rows of one (n,c) plane. Each thread: one float4 (4 pixels).
// Halo columns come from intra-wave shuffles (row = 32 contiguous lanes holds the
// whole 128-float row in its float4s) instead of 6 extra scalar loads per thread.
// Output stores are nontemporal: low/high are never re-read, and keeping them out
// of L2/L3 preserves x (loaded by pool_kernel, 134 MB < 256 MB L3) for the re-read.
__global__ __launch_bounds__(256) void main_kernel(const float* __restrict__ x,
                                                   const float* __restrict__ wk,
                                                   float* __restrict__ low,
                                                   float* __restrict__ high) {
    int b = blockIdx.x;
    int hblk = b & 15;                            // 16 row-blocks per plane
    int plane = b >> 4;                           // n*C + c
    int cc = plane & (C - 1);
    int nn = plane >> 8;
    int g = cc >> 5;                              // C/GROUP = 32 channels/group
    const float* wp = wk + ((size_t)nn * GROUP + g) * KK;   // block-uniform -> scalar loads
    float w0 = wp[0], w1 = wp[1], w2 = wp[2];
    float w3 = wp[3], w4 = wp[4], w5 = wp[5];
    float w6 = wp[6], w7 = wp[7], w8 = wp[8];

    int t = threadIdx.x;
    int r = t >> 5;                               // 0..7 row within block
    int l32 = t & 31;                             // lane within 32-lane row group
    int wb = l32 << 2;                            // 0,4,...,124
    int h = hblk * 8 + r;
    const float* xp = x + (size_t)plane * HW;

    int hm = (h == 0) ? 1 : h - 1;                // reflect pad (vertical)
    int hp = (h == H - 1) ? H - 2 : h + 1;

    float4 vm = *(const float4*)(xp + (size_t)hm * W + wb);
    float4 vc = *(const float4*)(xp + (size_t)h  * W + wb);
    float4 vp = *(const float4*)(xp + (size_t)hp * W + wb);

    // left/right halo via shuffle within the 32-lane row group; reflect at edges:
    //   wb==0   -> row[-1] reflects to row[1]   = v.y
    //   wb==124 -> row[128] reflects to row[126] = v.z
    float lm = __shfl_up(vm.w, 1, 32);
    float lc = __shfl_up(vc.w, 1, 32);
    float lp = __shfl_up(vp.w, 1, 32);
    float rm = __shfl_down(vm.x, 1, 32);
    float rc = __shfl_down(vc.x, 1, 32);
    float rp = __shfl_down(vp.x, 1, 32);
    if (l32 == 0)  { lm = vm.y; lc = vc.y; lp = vp.y; }
    if (l32 == 31) { rm = vm.z; rc = vc.z; rp = vp.z; }

    float a0[6] = {lm, vm.x, vm.y, vm.z, vm.w, rm};
    float a1[6] = {lc, vc.x, vc.y, vc.z, vc.w, rc};
    float a2[6] = {lp, vp.x, vp.y, vp.z, vp.w, rp};

    float lo[4];
#pragma unroll
    for (int k = 0; k < 4; ++k) {
        lo[k] = w0 * a0[k] + w1 * a0[k + 1] + w2 * a0[k + 2]
              + w3 * a1[k] + w4 * a1[k + 1] + w5 * a1[k + 2]
              + w6 * a2[k] + w7 * a2[k + 1] + w8 * a2[k + 2];
    }

    size_t oi = (size_t)plane * HW + (size_t)h * W + wb;
    f32x4 lov = {lo[0], lo[1], lo[2], lo[3]};
    f32x4 hiv = {vc.x - lo[0], vc.y - lo[1], vc.z - lo[2], vc.w - lo[3]};
    __builtin_nontemporal_store(lov, (f32x4*)(low + oi));
    __builtin_nontemporal_store(hiv, (f32x4*)(high + oi));
}

extern "C" void kernel_launch(void* const* d_in, const int* in_sizes, int n_in,
                              void* d_out, int out_size, void* d_ws, size_t ws_size,
                              hipStream_t stream) {
    const float* x      = (const float*)d_in[0];
    const float* conv_w = (const float*)d_in[1];
    const float* gate_w = (const float*)d_in[2];
    const float* gamma  = (const float*)d_in[3];
    const float* beta   = (const float*)d_in[4];
    const float* mean   = (const float*)d_in[5];
    const float* var    = (const float*)d_in[6];

    float* pooled = (float*)d_ws;                   // N*C = 4096 floats
    float* wkbuf  = pooled + N * C;                 // N*GK2 = 1152 floats

    float* low  = (float*)d_out;                    // N*C*H*W
    float* high = low + (size_t)N * C * H * W;

    pool_kernel<<<N * C, 256, 0, stream>>>(x, pooled);
    weights_kernel<<<N, 256, 0, stream>>>(pooled, conv_w, gate_w, gamma, beta, mean, var, wkbuf);
    main_kernel<<<N * C * (H / 8), 256, 0, stream>>>(x, wkbuf, low, high);
}